// Round 3
// baseline (504.847 us; speedup 1.0000x reference)
//
#include <hip/hip_runtime.h>

typedef __attribute__((ext_vector_type(4))) float f32x4;
typedef __attribute__((ext_vector_type(8))) short s16x8;
typedef __attribute__((ext_vector_type(8))) unsigned short u16x8;

#define IN_F 512
#define OUT_F 512
#define STYLE_F 256

__device__ __forceinline__ unsigned short f2bf(float f) {
    unsigned int u = __builtin_bit_cast(unsigned int, f);
    u += 0x7FFFu + ((u >> 16) & 1u);   // round-to-nearest-even
    return (unsigned short)(u >> 16);
}

// ---------------- prep1: alpha/beta GEMVs (2048 dots of length 256) --------
__global__ __launch_bounds__(256) void prep1_kernel(
    const float* __restrict__ z,
    const float* __restrict__ w_alpha,
    const float* __restrict__ b_alpha,
    const float* __restrict__ w_beta,
    const float* __restrict__ b_beta,
    float* __restrict__ alpha,
    float* __restrict__ beta)
{
    int gid = blockIdx.x * 256 + threadIdx.x;
    if (gid >= 2048) return;
    int t = gid & 1023;
    int b = t >> 9;
    int i = t & 511;
    const float* zr = z + b * STYLE_F;
    const float* wr = (gid < 1024 ? w_alpha : w_beta) + i * STYLE_F;
    float acc = 0.f;
    #pragma unroll 4
    for (int kk = 0; kk < STYLE_F; kk += 4) {
        float4 zv = *reinterpret_cast<const float4*>(zr + kk);
        float4 vv = *reinterpret_cast<const float4*>(wr + kk);
        acc += zv.x * vv.x + zv.y * vv.y + zv.z * vv.z + zv.w * vv.w;
    }
    if (gid < 1024) alpha[t] = acc + b_alpha[i];
    else            beta[t]  = acc + b_beta[i];
}

// ---------------- prep2: W * alpha_b -> bf16 fragment order, per batch -----
// wfragB[b] element index = (((ks*32 + nf)*64 + lane)*8 + e)
//   holds weight[n = nf*16 + (lane&15)][k = ks*32 + (lane>>4)*8 + e] * alpha[b][k]
__global__ __launch_bounds__(256) void prep2_kernel(
    const float* __restrict__ weight,
    const float* __restrict__ alpha,
    unsigned short* __restrict__ wfragB)
{
    int gid = blockIdx.x * 256 + threadIdx.x;   // 131072 threads total
    int b = gid >> 16;                          // 65536 threads per batch
    int f = (gid & 65535) << 2;
    int e0 = f & 7;                 // 0 or 4
    int l  = (f >> 3) & 63;
    int nf = (f >> 9) & 31;
    int ks = f >> 14;               // 0..15
    int n  = nf * 16 + (l & 15);
    int k  = ks * 32 + ((l >> 4) << 3) + e0;
    float4 wv = *reinterpret_cast<const float4*>(weight + n * IN_F + k);
    float4 av = *reinterpret_cast<const float4*>(alpha + b * IN_F + k);
    ushort4 o;
    o.x = f2bf(wv.x * av.x); o.y = f2bf(wv.y * av.y);
    o.z = f2bf(wv.z * av.z); o.w = f2bf(wv.w * av.w);
    *reinterpret_cast<ushort4*>(wfragB + b * 262144 + f) = o;
}

// ---------------- main GEMM: out = x_bf16 @ (W*alpha_b)^T + beta -----------
// BM=64, full N=512, full K=512 staged once. 512 threads = 8 waves (2M x 4N),
// wave tile 32x128 = 2x8 fragments of 16x16x32 bf16. ONE barrier per block.
__global__ __launch_bounds__(512, 4) void modlin_kernel(
    const float* __restrict__ x,
    const unsigned short* __restrict__ wfragB,
    const float* __restrict__ beta,
    float* __restrict__ out)
{
    // LDS: 64 rows x 512 k in bf16, 16B-unit XOR swizzle: unit u at row r
    // lives at byte r*1024 + ((u ^ (r&7)) << 4).
    __shared__ __align__(16) unsigned short lds[64 * 512];   // 64 KiB

    const int tid = threadIdx.x;
    const int mb  = blockIdx.x;                 // 4096 blocks
    const long long row0 = (long long)mb * 64;
    const int b = mb >> 11;                     // 2048 blocks per batch

    // ---- stage full 64x512 fp32 tile -> bf16 LDS (16 loads/thread upfront)
    {
        const int r = tid >> 3;                 // 0..63
        const int i = tid & 7;                  // 16B-unit low bits
        const float* xr = x + (row0 + r) * IN_F + i * 8;
        float4 v[16];
        #pragma unroll
        for (int c = 0; c < 8; c++) {
            v[2 * c]     = *reinterpret_cast<const float4*>(xr + c * 64);
            v[2 * c + 1] = *reinterpret_cast<const float4*>(xr + c * 64 + 4);
        }
        char* lb = (char*)lds;
        const int rbase = r * 1024;
        const int rx = r & 7;
        #pragma unroll
        for (int c = 0; c < 8; c++) {
            u16x8 h;
            h[0] = f2bf(v[2 * c].x);     h[1] = f2bf(v[2 * c].y);
            h[2] = f2bf(v[2 * c].z);     h[3] = f2bf(v[2 * c].w);
            h[4] = f2bf(v[2 * c + 1].x); h[5] = f2bf(v[2 * c + 1].y);
            h[6] = f2bf(v[2 * c + 1].z); h[7] = f2bf(v[2 * c + 1].w);
            int u = c * 8 + i;
            *reinterpret_cast<u16x8*>(lb + rbase + ((u ^ rx) << 4)) = h;
        }
    }
    __syncthreads();   // the only barrier

    // ---- wave / fragment map
    const int l  = tid & 63;
    const int w  = tid >> 6;
    const int wm = w >> 2;           // 0..1  (M)
    const int wn = w & 3;            // 0..3  (N)
    const int fr = l & 15;
    const int fq = l >> 4;           // 0..3

    const unsigned short* bbase = wfragB + (size_t)b * 262144
                                + ((size_t)(wn * 8) * 64 + l) * 8;

    f32x4 acc[2][8];
    #pragma unroll
    for (int i = 0; i < 2; i++)
        #pragma unroll
        for (int j = 0; j < 8; j++)
            acc[i][j] = (f32x4){0.f, 0.f, 0.f, 0.f};

    const char* lb = (const char*)lds;
    const int row0l = wm * 32 + fr;
    const int row1l = row0l + 16;
    const int sw0 = (row0l & 7) << 4;
    const int sw1 = (row1l & 7) << 4;
    const int rb0 = row0l * 1024;
    const int rb1 = row1l * 1024;

    // ---- barrier-free compute: 16 k-slices of 32
    for (int s = 0; s < 16; s++) {
        const int ub = (s * 4 + fq) << 4;       // unit byte offset
        s16x8 a0 = *reinterpret_cast<const s16x8*>(lb + rb0 + (ub ^ sw0));
        s16x8 a1 = *reinterpret_cast<const s16x8*>(lb + rb1 + (ub ^ sw1));
        const unsigned short* bp = bbase + s * 16384;
        #pragma unroll
        for (int nf = 0; nf < 8; nf++) {
            s16x8 bf = *reinterpret_cast<const s16x8*>(bp + nf * 512);
            acc[0][nf] = __builtin_amdgcn_mfma_f32_16x16x32_bf16(a0, bf, acc[0][nf], 0, 0, 0);
            acc[1][nf] = __builtin_amdgcn_mfma_f32_16x16x32_bf16(a1, bf, acc[1][nf], 0, 0, 0);
        }
    }

    // ---- epilogue: add beta, store fp32
    const float* brow = beta + b * OUT_F;
    #pragma unroll
    for (int nf = 0; nf < 8; nf++) {
        int col = wn * 128 + nf * 16 + fr;
        float bv = brow[col];
        #pragma unroll
        for (int mf = 0; mf < 2; mf++) {
            long long r = row0 + wm * 32 + mf * 16 + fq * 4;
            float* op = out + r * OUT_F + col;
            op[0 * OUT_F] = acc[mf][nf][0] + bv;
            op[1 * OUT_F] = acc[mf][nf][1] + bv;
            op[2 * OUT_F] = acc[mf][nf][2] + bv;
            op[3 * OUT_F] = acc[mf][nf][3] + bv;
        }
    }
}

extern "C" void kernel_launch(void* const* d_in, const int* in_sizes, int n_in,
                              void* d_out, int out_size, void* d_ws, size_t ws_size,
                              hipStream_t stream)
{
    const float* x       = (const float*)d_in[0];
    const float* z       = (const float*)d_in[1];
    const float* weight  = (const float*)d_in[2];
    const float* w_alpha = (const float*)d_in[3];
    const float* b_alpha = (const float*)d_in[4];
    const float* w_beta  = (const float*)d_in[5];
    const float* b_beta  = (const float*)d_in[6];
    float* out = (float*)d_out;

    unsigned short* wfragB = (unsigned short*)d_ws;          // 2 x 512 KiB
    float* alpha = (float*)((char*)d_ws + 1048576);          // 4 KiB
    float* beta  = alpha + 2 * IN_F;                         // 4 KiB

    prep1_kernel<<<8, 256, 0, stream>>>(z, w_alpha, b_alpha, w_beta, b_beta,
                                        alpha, beta);
    prep2_kernel<<<512, 256, 0, stream>>>(weight, alpha, wfragB);
    modlin_kernel<<<4096, 512, 0, stream>>>(x, wfragB, beta, out);
}